// Round 3
// baseline (2605.141 us; speedup 1.0000x reference)
//
#include <hip/hip_runtime.h>
#include <hip/hip_bf16.h>

#define NEXP  8
#define DM    1024
#define VOCAB 32000
#define BATCH 4096
#define TM    128
#define TN    128
#define BK    32
#define NKT   (DM / BK)   // 32 k-steps

typedef short bf16x8 __attribute__((ext_vector_type(8)));
typedef float f32x4  __attribute__((ext_vector_type(4)));

// ---------------- routing: counts -> offsets -> permutation ----------------
__global__ void route_kernel(const int* __restrict__ ptr,
                             int* __restrict__ gstart,
                             int* __restrict__ perm)
{
    __shared__ int cnt[NEXP];
    __shared__ int cur[NEXP];
    int tid = threadIdx.x;
    if (tid < NEXP) cnt[tid] = 0;
    __syncthreads();
    for (int r = tid; r < BATCH; r += blockDim.x) {
        int e = ptr[r] & (NEXP - 1);
        atomicAdd(&cnt[e], 1);
    }
    __syncthreads();
    if (tid == 0) {
        int acc = 0;
        for (int e = 0; e < NEXP; ++e) {
            gstart[e] = acc;
            cur[e] = acc;
            acc += cnt[e];
        }
        gstart[NEXP] = acc; // == BATCH
    }
    __syncthreads();
    for (int r = tid; r < BATCH; r += blockDim.x) {
        int e = ptr[r] & (NEXP - 1);
        int pos = atomicAdd(&cur[e], 1);
        perm[pos] = r;
    }
}

// ---------------- gather x rows -> group-contiguous bf16 A ----------------
__global__ void pack_kernel(const float* __restrict__ x,
                            const int* __restrict__ perm,
                            __hip_bfloat16* __restrict__ Ap)
{
    int p   = blockIdx.x;
    int tid = threadIdx.x;
    __hip_bfloat16* dst = Ap + (size_t)p * DM + tid * 4;
    if (p >= BATCH) {
        *(unsigned long long*)dst = 0ull;
        return;
    }
    int r = perm[p];
    const float4 v = *(const float4*)(x + (size_t)r * DM + tid * 4);
    union { __hip_bfloat162 h[2]; unsigned long long q; } cv;
    cv.h[0] = __float22bfloat162_rn(make_float2(v.x, v.y));
    cv.h[1] = __float22bfloat162_rn(make_float2(v.z, v.w));
    *(unsigned long long*)dst = cv.q;
}

// ======== staging / compute macros (named __shared__ buffers only) ========
#define STAGE_A(DST, KOFF)                                                    \
    _Pragma("unroll")                                                         \
    for (int t = 0; t < 2; ++t) {                                             \
        const __hip_bfloat16* src =                                           \
            Ab + (size_t)(t * 64 + arow) * DM + (KOFF) + acol;                \
        __builtin_amdgcn_global_load_lds(                                     \
            (const __attribute__((address_space(1))) void*)src,               \
            (__attribute__((address_space(3))) void*)(DST + (t * 64 + wave * 16) * BK), \
            16, 0, 0);                                                        \
    }

#define LOAD_B_REG(PV, KOFF)                                                  \
    _Pragma("unroll")                                                         \
    for (int t = 0; t < 4; ++t)                                               \
        PV[t] = *(const float4*)(Wb + (size_t)b_row[t] * DM + (KOFF) + b_c4[t]);

#define WRITE_B_LDS(DST, PV)                                                  \
    _Pragma("unroll")                                                         \
    for (int t = 0; t < 4; ++t) {                                             \
        union { __hip_bfloat162 h2[2]; unsigned long long q; } cv;            \
        cv.h2[0] = __float22bfloat162_rn(make_float2(PV[t].x, PV[t].y));      \
        cv.h2[1] = __float22bfloat162_rn(make_float2(PV[t].z, PV[t].w));      \
        *(unsigned long long*)(DST + b_row[t] * BK + b_c4[t]) = cv.q;         \
    }

#define COMPUTE(SRCA, SRCB)                                                   \
    {                                                                         \
        bf16x8 av[4], bv[4];                                                  \
        _Pragma("unroll")                                                     \
        for (int i = 0; i < 4; ++i)                                           \
            av[i] = *(const bf16x8*)(SRCA + (wm + i * 16 + l16) * BK + quad * 8); \
        _Pragma("unroll")                                                     \
        for (int j = 0; j < 4; ++j)                                           \
            bv[j] = *(const bf16x8*)(SRCB + (wn + j * 16 + l16) * BK + quad * 8); \
        _Pragma("unroll")                                                     \
        for (int i = 0; i < 4; ++i)                                           \
            _Pragma("unroll")                                                 \
            for (int j = 0; j < 4; ++j)                                       \
                acc[i][j] = __builtin_amdgcn_mfma_f32_16x16x32_bf16(          \
                    av[i], bv[j], acc[i][j], 0, 0, 0);                        \
    }

// ---------------- grouped GEMM, persistent blocks + 2-phase dbuf ----------
// grid = (VOCAB/TN = 250, NEXP = 8). Each block loops its expert's m-tiles.
// K-loop: T3-minimum double-buffer — stage(next) issued before compute(cur),
// one __syncthreads per K-step (implicit full drain makes this race-free).
__global__ __launch_bounds__(256) void moe_gemm_kernel(
    const __hip_bfloat16* __restrict__ Ap,   // [BATCH+TM][DM] bf16, grouped
    const float* __restrict__ W,             // [E][VOCAB][DM] fp32
    const float* __restrict__ bias,          // [E][VOCAB] fp32
    const int* __restrict__ gstart,          // [E+1]
    const int* __restrict__ perm,            // [BATCH]
    float* __restrict__ out)                 // [BATCH][VOCAB] fp32
{
    const int nt = blockIdx.x;
    const int e  = blockIdx.y;
    const int g0 = gstart[e];
    const int ne = gstart[e + 1] - g0;
    if (ne <= 0) return;
    const int nmt = (ne + TM - 1) / TM;
    const int n0  = nt * TN;

    __shared__ __hip_bfloat16 Asm0[TM * BK];  // 8 KB each, 32 KB total
    __shared__ __hip_bfloat16 Asm1[TM * BK];
    __shared__ __hip_bfloat16 Bsm0[TN * BK];
    __shared__ __hip_bfloat16 Bsm1[TN * BK];

    const int tid  = threadIdx.x;
    const int lane = tid & 63;
    const int wave = tid >> 6;
    const int wm   = (wave & 1) * 64;
    const int wn   = (wave >> 1) * 64;
    const int l16  = lane & 15;
    const int quad = lane >> 4;

    // A staging geometry: 64 lanes x 16B = 16 rows of [32 bf16] per instr
    const int arow = wave * 16 + (lane >> 2);
    const int acol = (lane & 3) * 8;

    // B staging geometry: 4 units/thread, 8B each
    int b_row[4], b_c4[4];
    #pragma unroll
    for (int t = 0; t < 4; ++t) {
        int u = t * 256 + tid;
        b_row[t] = u >> 3;
        b_c4[t]  = (u & 7) * 4;
    }

    const float* Wb = W + ((size_t)e * VOCAB + n0) * DM;

    float bj[4];
    #pragma unroll
    for (int j = 0; j < 4; ++j)
        bj[j] = bias[(size_t)e * VOCAB + n0 + wn + j * 16 + l16];

    for (int mt = 0; mt < nmt; ++mt) {
        const int m0 = mt * TM;
        const __hip_bfloat16* Ab = Ap + (size_t)(g0 + m0) * DM;
        f32x4 acc[4][4] = {};
        float4 pv[4];

        // ---- prologue: stage k-tile 0 into buf0 ----
        STAGE_A(Asm0, 0)
        LOAD_B_REG(pv, 0)
        WRITE_B_LDS(Bsm0, pv)
        __syncthreads();

        for (int kh = 0; kh < NKT / 2; ++kh) {
            const int ke = 2 * kh + 1;
            // even step: stage buf1 @ ke (in flight), compute buf0
            STAGE_A(Asm1, ke * BK)
            LOAD_B_REG(pv, ke * BK)
            COMPUTE(Asm0, Bsm0)
            WRITE_B_LDS(Bsm1, pv)
            __syncthreads();
            // odd step: stage buf0 @ ke+1 (skip on last), compute buf1
            if (kh + 1 < NKT / 2) {
                STAGE_A(Asm0, (ke + 1) * BK)
                LOAD_B_REG(pv, (ke + 1) * BK)
            }
            COMPUTE(Asm1, Bsm1)
            if (kh + 1 < NKT / 2) {
                WRITE_B_LDS(Bsm0, pv)
            }
            __syncthreads();
        }

        // ---- epilogue (proven): bias + scatter through perm ----
        // C/D layout: col = lane&15, row = quad*4 + reg
        #pragma unroll
        for (int j = 0; j < 4; ++j) {
            const int col = n0 + wn + j * 16 + l16;
            const float bv_ = bj[j];
            #pragma unroll
            for (int i = 0; i < 4; ++i) {
                #pragma unroll
                for (int r = 0; r < 4; ++r) {
                    int pr = m0 + wm + i * 16 + quad * 4 + r;
                    if (pr < ne) {
                        int orow = perm[g0 + pr];
                        out[(size_t)orow * VOCAB + col] = acc[i][j][r] + bv_;
                    }
                }
            }
        }
        // epilogue touches no LDS; the prologue of the next m-tile writes
        // buffers whose last reads were drained by the final K-step barrier
    }
}

extern "C" void kernel_launch(void* const* d_in, const int* in_sizes, int n_in,
                              void* d_out, int out_size, void* d_ws, size_t ws_size,
                              hipStream_t stream)
{
    const float* x   = (const float*)d_in[0];
    const int*   ptr = (const int*)d_in[1];
    const float* W   = (const float*)d_in[2];
    const float* b   = (const float*)d_in[3];
    float* out = (float*)d_out;

    char* ws = (char*)d_ws;
    int* gstart = (int*)ws;                              // 16 ints
    int* perm   = (int*)(ws + 64);                       // 4096 ints
    __hip_bfloat16* Ap = (__hip_bfloat16*)(ws + 32768);  // (4096+128)*1024 bf16

    route_kernel<<<1, 256, 0, stream>>>(ptr, gstart, perm);
    pack_kernel<<<BATCH + TM, 256, 0, stream>>>(x, perm, Ap);
    dim3 grid(VOCAB / TN, NEXP);
    moe_gemm_kernel<<<grid, 256, 0, stream>>>(Ap, W, b, gstart, perm, out);
}

// Round 4
// 2291.100 us; speedup vs baseline: 1.1371x; 1.1371x over previous
//
#include <hip/hip_runtime.h>
#include <hip/hip_bf16.h>

#define NEXP  8
#define DM    1024
#define VOCAB 32000
#define BATCH 4096
#define TM    128
#define TN    128
#define BK    32

typedef short bf16x8 __attribute__((ext_vector_type(8)));
typedef float f32x4  __attribute__((ext_vector_type(4)));

// workspace layout
#define WS_PERM_OFF   64
#define WS_AP_OFF     32768
#define WS_WB_OFF     16777216ull                       // 16 MB, aligned
#define WS_WB_BYTES   ((size_t)NEXP * VOCAB * DM * 2)   // 524,288,000
#define WS_NEED       (WS_WB_OFF + WS_WB_BYTES)

// ---------------- routing: counts -> offsets -> permutation ----------------
__global__ void route_kernel(const int* __restrict__ ptr,
                             int* __restrict__ gstart,
                             int* __restrict__ perm)
{
    __shared__ int cnt[NEXP];
    __shared__ int cur[NEXP];
    int tid = threadIdx.x;
    if (tid < NEXP) cnt[tid] = 0;
    __syncthreads();
    for (int r = tid; r < BATCH; r += blockDim.x) {
        int e = ptr[r] & (NEXP - 1);
        atomicAdd(&cnt[e], 1);
    }
    __syncthreads();
    if (tid == 0) {
        int acc = 0;
        for (int e = 0; e < NEXP; ++e) {
            gstart[e] = acc;
            cur[e] = acc;
            acc += cnt[e];
        }
        gstart[NEXP] = acc; // == BATCH
    }
    __syncthreads();
    for (int r = tid; r < BATCH; r += blockDim.x) {
        int e = ptr[r] & (NEXP - 1);
        int pos = atomicAdd(&cur[e], 1);
        perm[pos] = r;
    }
}

// ---------------- gather x rows -> group-contiguous bf16 A ----------------
__global__ void pack_kernel(const float* __restrict__ x,
                            const int* __restrict__ perm,
                            __hip_bfloat16* __restrict__ Ap)
{
    int p   = blockIdx.x;
    int tid = threadIdx.x;
    __hip_bfloat16* dst = Ap + (size_t)p * DM + tid * 4;
    if (p >= BATCH) {
        *(unsigned long long*)dst = 0ull;
        return;
    }
    int r = perm[p];
    const float4 v = *(const float4*)(x + (size_t)r * DM + tid * 4);
    union { __hip_bfloat162 h[2]; unsigned long long q; } cv;
    cv.h[0] = __float22bfloat162_rn(make_float2(v.x, v.y));
    cv.h[1] = __float22bfloat162_rn(make_float2(v.z, v.w));
    *(unsigned long long*)dst = cv.q;
}

// ---------------- one-time W fp32 -> bf16 convert (streaming) --------------
typedef unsigned short u16x8 __attribute__((ext_vector_type(8)));

__global__ void wconv_kernel(const float* __restrict__ W,
                             __hip_bfloat16* __restrict__ Wb)
{
    const size_t total = (size_t)NEXP * VOCAB * DM / 8;  // u16x8 units
    const size_t stride = (size_t)gridDim.x * blockDim.x;
    for (size_t u = (size_t)blockIdx.x * blockDim.x + threadIdx.x;
         u < total; u += stride) {
        const float4 a = *(const float4*)(W + u * 8);
        const float4 b = *(const float4*)(W + u * 8 + 4);
        union { __hip_bfloat162 h[4]; u16x8 q; } cv;
        cv.h[0] = __float22bfloat162_rn(make_float2(a.x, a.y));
        cv.h[1] = __float22bfloat162_rn(make_float2(a.z, a.w));
        cv.h[2] = __float22bfloat162_rn(make_float2(b.x, b.y));
        cv.h[3] = __float22bfloat162_rn(make_float2(b.z, b.w));
        *(u16x8*)(Wb + u * 8) = cv.q;
    }
}

// ============ GEMM variant 1 (preferred): bf16 W, all-gload_lds ============
// Persistent (n-tile, expert) grid; m97-structure K-loop: both operands via
// global_load_lds width=16, no VALU staging, 2 barriers per K-step.
__global__ __launch_bounds__(256) void moe_gemm_bf16(
    const __hip_bfloat16* __restrict__ Ap,   // [BATCH+TM][DM] bf16, grouped
    const __hip_bfloat16* __restrict__ Wb16, // [E][VOCAB][DM] bf16
    const float* __restrict__ bias,          // [E][VOCAB] fp32
    const int* __restrict__ gstart,          // [E+1]
    const int* __restrict__ perm,            // [BATCH]
    float* __restrict__ out)                 // [BATCH][VOCAB] fp32
{
    const int nt = blockIdx.x;
    const int e  = blockIdx.y;
    const int g0 = gstart[e];
    const int ne = gstart[e + 1] - g0;
    if (ne <= 0) return;
    const int nmt = (ne + TM - 1) / TM;
    const int n0  = nt * TN;

    __shared__ __hip_bfloat16 Asm[TM * BK];  // 8 KB
    __shared__ __hip_bfloat16 Bsm[TN * BK];  // 8 KB

    const int tid  = threadIdx.x;
    const int lane = tid & 63;
    const int wave = tid >> 6;
    const int wm   = (wave & 1) * 64;
    const int wn   = (wave >> 1) * 64;
    const int l16  = lane & 15;
    const int quad = lane >> 4;

    // staging geometry (identical for A and B tiles: 128 rows x 32 bf16):
    // per wave-instr 64 lanes x 16B = 16 rows
    const int arow = wave * 16 + (lane >> 2);
    const int acol = (lane & 3) * 8;

    const __hip_bfloat16* Wbb = Wb16 + ((size_t)e * VOCAB + n0) * DM;

    float bj[4];
    #pragma unroll
    for (int j = 0; j < 4; ++j)
        bj[j] = bias[(size_t)e * VOCAB + n0 + wn + j * 16 + l16];

    for (int mt = 0; mt < nmt; ++mt) {
        const int m0 = mt * TM;
        const __hip_bfloat16* Ab = Ap + (size_t)(g0 + m0) * DM;
        f32x4 acc[4][4] = {};

        for (int k0 = 0; k0 < DM; k0 += BK) {
            __syncthreads();
            #pragma unroll
            for (int t = 0; t < 2; ++t) {
                const __hip_bfloat16* srcA = Ab + (size_t)(t * 64 + arow) * DM + k0 + acol;
                __builtin_amdgcn_global_load_lds(
                    (const __attribute__((address_space(1))) void*)srcA,
                    (__attribute__((address_space(3))) void*)(Asm + (t * 64 + wave * 16) * BK),
                    16, 0, 0);
                const __hip_bfloat16* srcB = Wbb + (size_t)(t * 64 + arow) * DM + k0 + acol;
                __builtin_amdgcn_global_load_lds(
                    (const __attribute__((address_space(1))) void*)srcB,
                    (__attribute__((address_space(3))) void*)(Bsm + (t * 64 + wave * 16) * BK),
                    16, 0, 0);
            }
            __syncthreads();
            bf16x8 av[4], bv[4];
            #pragma unroll
            for (int i = 0; i < 4; ++i)
                av[i] = *(const bf16x8*)(Asm + (wm + i * 16 + l16) * BK + quad * 8);
            #pragma unroll
            for (int j = 0; j < 4; ++j)
                bv[j] = *(const bf16x8*)(Bsm + (wn + j * 16 + l16) * BK + quad * 8);
            #pragma unroll
            for (int i = 0; i < 4; ++i)
                #pragma unroll
                for (int j = 0; j < 4; ++j)
                    acc[i][j] = __builtin_amdgcn_mfma_f32_16x16x32_bf16(
                        av[i], bv[j], acc[i][j], 0, 0, 0);
        }

        // epilogue: C/D layout col = lane&15, row = quad*4 + reg
        #pragma unroll
        for (int j = 0; j < 4; ++j) {
            const int col = n0 + wn + j * 16 + l16;
            const float bv_ = bj[j];
            #pragma unroll
            for (int i = 0; i < 4; ++i) {
                #pragma unroll
                for (int r = 0; r < 4; ++r) {
                    int pr = m0 + wm + i * 16 + quad * 4 + r;
                    if (pr < ne) {
                        int orow = perm[g0 + pr];
                        out[(size_t)orow * VOCAB + col] = acc[i][j][r] + bv_;
                    }
                }
            }
        }
    }
}

// ============ GEMM variant 2 (fallback, proven R2): fp32 W convert =========
__global__ __launch_bounds__(256) void moe_gemm_kernel(
    const __hip_bfloat16* __restrict__ Ap,
    const float* __restrict__ W,
    const float* __restrict__ bias,
    const int* __restrict__ gstart,
    const int* __restrict__ perm,
    float* __restrict__ out)
{
    const int nt = blockIdx.x;
    const int e  = blockIdx.y;
    const int g0 = gstart[e];
    const int ne = gstart[e + 1] - g0;
    if (ne <= 0) return;
    const int nmt = (ne + TM - 1) / TM;
    const int n0  = nt * TN;

    __shared__ __hip_bfloat16 Asm[TM * BK];
    __shared__ __hip_bfloat16 Bsm[TN * BK];

    const int tid  = threadIdx.x;
    const int lane = tid & 63;
    const int wave = tid >> 6;
    const int wm   = (wave & 1) * 64;
    const int wn   = (wave >> 1) * 64;
    const int l16  = lane & 15;
    const int quad = lane >> 4;

    const int arow = wave * 16 + (lane >> 2);
    const int acol = (lane & 3) * 8;

    const float* Wb = W + ((size_t)e * VOCAB + n0) * DM;

    float bj[4];
    #pragma unroll
    for (int j = 0; j < 4; ++j)
        bj[j] = bias[(size_t)e * VOCAB + n0 + wn + j * 16 + l16];

    for (int mt = 0; mt < nmt; ++mt) {
        const int m0 = mt * TM;
        const __hip_bfloat16* Ab = Ap + (size_t)(g0 + m0) * DM;
        f32x4 acc[4][4] = {};

        for (int k0 = 0; k0 < DM; k0 += BK) {
            __syncthreads();
            #pragma unroll
            for (int t = 0; t < 2; ++t) {
                const __hip_bfloat16* src = Ab + (size_t)(t * 64 + arow) * DM + k0 + acol;
                __builtin_amdgcn_global_load_lds(
                    (const __attribute__((address_space(1))) void*)src,
                    (__attribute__((address_space(3))) void*)(Asm + (t * 64 + wave * 16) * BK),
                    16, 0, 0);
            }
            #pragma unroll
            for (int t = 0; t < 4; ++t) {
                int u   = t * 256 + tid;
                int row = u >> 3;
                int c4  = (u & 7) * 4;
                const float4 v = *(const float4*)(Wb + (size_t)row * DM + k0 + c4);
                union { __hip_bfloat162 h[2]; unsigned long long q; } cv;
                cv.h[0] = __float22bfloat162_rn(make_float2(v.x, v.y));
                cv.h[1] = __float22bfloat162_rn(make_float2(v.z, v.w));
                *(unsigned long long*)(Bsm + row * BK + c4) = cv.q;
            }
            __syncthreads();
            bf16x8 av[4], bv[4];
            #pragma unroll
            for (int i = 0; i < 4; ++i)
                av[i] = *(const bf16x8*)(Asm + (wm + i * 16 + l16) * BK + quad * 8);
            #pragma unroll
            for (int j = 0; j < 4; ++j)
                bv[j] = *(const bf16x8*)(Bsm + (wn + j * 16 + l16) * BK + quad * 8);
            #pragma unroll
            for (int i = 0; i < 4; ++i)
                #pragma unroll
                for (int j = 0; j < 4; ++j)
                    acc[i][j] = __builtin_amdgcn_mfma_f32_16x16x32_bf16(
                        av[i], bv[j], acc[i][j], 0, 0, 0);
        }

        #pragma unroll
        for (int j = 0; j < 4; ++j) {
            const int col = n0 + wn + j * 16 + l16;
            const float bv_ = bj[j];
            #pragma unroll
            for (int i = 0; i < 4; ++i) {
                #pragma unroll
                for (int r = 0; r < 4; ++r) {
                    int pr = m0 + wm + i * 16 + quad * 4 + r;
                    if (pr < ne) {
                        int orow = perm[g0 + pr];
                        out[(size_t)orow * VOCAB + col] = acc[i][j][r] + bv_;
                    }
                }
            }
        }
    }
}

extern "C" void kernel_launch(void* const* d_in, const int* in_sizes, int n_in,
                              void* d_out, int out_size, void* d_ws, size_t ws_size,
                              hipStream_t stream)
{
    const float* x   = (const float*)d_in[0];
    const int*   ptr = (const int*)d_in[1];
    const float* W   = (const float*)d_in[2];
    const float* b   = (const float*)d_in[3];
    float* out = (float*)d_out;

    char* ws = (char*)d_ws;
    int* gstart = (int*)ws;
    int* perm   = (int*)(ws + WS_PERM_OFF);
    __hip_bfloat16* Ap = (__hip_bfloat16*)(ws + WS_AP_OFF);

    route_kernel<<<1, 256, 0, stream>>>(ptr, gstart, perm);
    pack_kernel<<<BATCH + TM, 256, 0, stream>>>(x, perm, Ap);

    dim3 grid(VOCAB / TN, NEXP);
    if (ws_size >= WS_NEED) {
        __hip_bfloat16* Wb16 = (__hip_bfloat16*)(ws + WS_WB_OFF);
        wconv_kernel<<<2048, 256, 0, stream>>>(W, Wb16);
        moe_gemm_bf16<<<grid, 256, 0, stream>>>(Ap, Wb16, b, gstart, perm, out);
    } else {
        moe_gemm_kernel<<<grid, 256, 0, stream>>>(Ap, W, b, gstart, perm, out);
    }
}

// Round 5
// 2115.823 us; speedup vs baseline: 1.2313x; 1.0828x over previous
//
#include <hip/hip_runtime.h>
#include <hip/hip_bf16.h>

#define NEXP  8
#define DM    1024
#define VOCAB 32000
#define BATCH 4096
#define TM    128      // fallback kernel tile
#define TMB   256      // big-tile M (bf16 kernel)
#define TNB   128
#define BK    32

typedef short bf16x8 __attribute__((ext_vector_type(8)));
typedef float f32x4  __attribute__((ext_vector_type(4)));

// workspace layout
#define WS_PERM_OFF   64
#define WS_AP_OFF     32768
#define WS_WB_OFF     16777216ull                       // 16 MB, aligned
#define WS_WB_BYTES   ((size_t)NEXP * VOCAB * DM * 2)   // 524,288,000
#define WS_NEED       (WS_WB_OFF + WS_WB_BYTES)

// ---------------- routing: counts -> offsets -> permutation ----------------
__global__ void route_kernel(const int* __restrict__ ptr,
                             int* __restrict__ gstart,
                             int* __restrict__ perm)
{
    __shared__ int cnt[NEXP];
    __shared__ int cur[NEXP];
    int tid = threadIdx.x;
    if (tid < NEXP) cnt[tid] = 0;
    __syncthreads();
    for (int r = tid; r < BATCH; r += blockDim.x) {
        int e = ptr[r] & (NEXP - 1);
        atomicAdd(&cnt[e], 1);
    }
    __syncthreads();
    if (tid == 0) {
        int acc = 0;
        for (int e = 0; e < NEXP; ++e) {
            gstart[e] = acc;
            cur[e] = acc;
            acc += cnt[e];
        }
        gstart[NEXP] = acc; // == BATCH
    }
    __syncthreads();
    for (int r = tid; r < BATCH; r += blockDim.x) {
        int e = ptr[r] & (NEXP - 1);
        int pos = atomicAdd(&cur[e], 1);
        perm[pos] = r;
    }
}

// ---------------- gather x rows -> group-contiguous bf16 A ----------------
// grid = BATCH + TMB blocks (pad rows zero-filled)
__global__ void pack_kernel(const float* __restrict__ x,
                            const int* __restrict__ perm,
                            __hip_bfloat16* __restrict__ Ap)
{
    int p   = blockIdx.x;
    int tid = threadIdx.x;
    __hip_bfloat16* dst = Ap + (size_t)p * DM + tid * 4;
    if (p >= BATCH) {
        *(unsigned long long*)dst = 0ull;
        return;
    }
    int r = perm[p];
    const float4 v = *(const float4*)(x + (size_t)r * DM + tid * 4);
    union { __hip_bfloat162 h[2]; unsigned long long q; } cv;
    cv.h[0] = __float22bfloat162_rn(make_float2(v.x, v.y));
    cv.h[1] = __float22bfloat162_rn(make_float2(v.z, v.w));
    *(unsigned long long*)dst = cv.q;
}

// ---------------- one-time W fp32 -> bf16 convert (streaming) --------------
typedef unsigned short u16x8 __attribute__((ext_vector_type(8)));

__global__ void wconv_kernel(const float* __restrict__ W,
                             __hip_bfloat16* __restrict__ Wb)
{
    const size_t total = (size_t)NEXP * VOCAB * DM / 8;  // u16x8 units
    const size_t stride = (size_t)gridDim.x * blockDim.x;
    for (size_t u = (size_t)blockIdx.x * blockDim.x + threadIdx.x;
         u < total; u += stride) {
        const float4 a = *(const float4*)(W + u * 8);
        const float4 b = *(const float4*)(W + u * 8 + 4);
        union { __hip_bfloat162 h[4]; u16x8 q; } cv;
        cv.h[0] = __float22bfloat162_rn(make_float2(a.x, a.y));
        cv.h[1] = __float22bfloat162_rn(make_float2(a.z, a.w));
        cv.h[2] = __float22bfloat162_rn(make_float2(b.x, b.y));
        cv.h[3] = __float22bfloat162_rn(make_float2(b.z, b.w));
        *(u16x8*)(Wb + u * 8) = cv.q;
    }
}

// ============ GEMM variant 1 (preferred): bf16 W, TMB=256, 8 waves ==========
// Persistent (n-tile, expert) grid; single-buffer 2-barrier K-loop (proven);
// 256-row m-tiles halve both the drain count and the W slab re-reads.
__global__ __launch_bounds__(512) void moe_gemm_bf16(
    const __hip_bfloat16* __restrict__ Ap,   // [BATCH+TMB][DM] bf16, grouped
    const __hip_bfloat16* __restrict__ Wb16, // [E][VOCAB][DM] bf16
    const float* __restrict__ bias,          // [E][VOCAB] fp32
    const int* __restrict__ gstart,          // [E+1]
    const int* __restrict__ perm,            // [BATCH]
    float* __restrict__ out)                 // [BATCH][VOCAB] fp32
{
    const int nt = blockIdx.x;
    const int e  = blockIdx.y;
    const int g0 = gstart[e];
    const int ne = gstart[e + 1] - g0;
    if (ne <= 0) return;
    const int nmt = (ne + TMB - 1) / TMB;
    const int n0  = nt * TNB;

    __shared__ __hip_bfloat16 Asm[TMB * BK];  // 16 KB
    __shared__ __hip_bfloat16 Bsm[TNB * BK];  // 8 KB

    const int tid  = threadIdx.x;
    const int lane = tid & 63;
    const int wave = tid >> 6;          // 0..7
    const int wm   = (wave & 3) * 64;   // 4 m-waves
    const int wn   = (wave >> 2) * 64;  // 2 n-waves
    const int l16  = lane & 15;
    const int quad = lane >> 4;

    // staging geometry: per wave-instr 64 lanes x 16B = 16 rows of [32 bf16]
    const int srow = lane >> 2;         // 0..15
    const int scol = (lane & 3) * 8;    // bf16 elems within BK

    const __hip_bfloat16* Wbb = Wb16 + ((size_t)e * VOCAB + n0) * DM;

    float bj[4];
    #pragma unroll
    for (int j = 0; j < 4; ++j)
        bj[j] = bias[(size_t)e * VOCAB + n0 + wn + j * 16 + l16];

    for (int mt = 0; mt < nmt; ++mt) {
        const int m0 = mt * TMB;
        const __hip_bfloat16* Ab = Ap + (size_t)(g0 + m0) * DM;
        f32x4 acc[4][4] = {};

        for (int k0 = 0; k0 < DM; k0 += BK) {
            __syncthreads();
            // ---- stage A tile: 256 rows; wave stages rows wave*32 + t*16 ----
            #pragma unroll
            for (int t = 0; t < 2; ++t) {
                const __hip_bfloat16* srcA =
                    Ab + (size_t)(wave * 32 + t * 16 + srow) * DM + k0 + scol;
                __builtin_amdgcn_global_load_lds(
                    (const __attribute__((address_space(1))) void*)srcA,
                    (__attribute__((address_space(3))) void*)(Asm + (wave * 32 + t * 16) * BK),
                    16, 0, 0);
            }
            // ---- stage B tile: 128 rows; wave stages rows wave*16.. ----
            {
                const __hip_bfloat16* srcB =
                    Wbb + (size_t)(wave * 16 + srow) * DM + k0 + scol;
                __builtin_amdgcn_global_load_lds(
                    (const __attribute__((address_space(1))) void*)srcB,
                    (__attribute__((address_space(3))) void*)(Bsm + (wave * 16) * BK),
                    16, 0, 0);
            }
            __syncthreads();
            // ---- fragments + MFMA 4x4 of 16x16x32 per wave ----
            bf16x8 av[4], bv[4];
            #pragma unroll
            for (int i = 0; i < 4; ++i)
                av[i] = *(const bf16x8*)(Asm + (wm + i * 16 + l16) * BK + quad * 8);
            #pragma unroll
            for (int j = 0; j < 4; ++j)
                bv[j] = *(const bf16x8*)(Bsm + (wn + j * 16 + l16) * BK + quad * 8);
            #pragma unroll
            for (int i = 0; i < 4; ++i)
                #pragma unroll
                for (int j = 0; j < 4; ++j)
                    acc[i][j] = __builtin_amdgcn_mfma_f32_16x16x32_bf16(
                        av[i], bv[j], acc[i][j], 0, 0, 0);
        }

        // ---- epilogue (proven): C/D layout col = lane&15, row = quad*4+reg --
        #pragma unroll
        for (int j = 0; j < 4; ++j) {
            const int col = n0 + wn + j * 16 + l16;
            const float bv_ = bj[j];
            #pragma unroll
            for (int i = 0; i < 4; ++i) {
                #pragma unroll
                for (int r = 0; r < 4; ++r) {
                    int pr = m0 + wm + i * 16 + quad * 4 + r;
                    if (pr < ne) {
                        int orow = perm[g0 + pr];
                        out[(size_t)orow * VOCAB + col] = acc[i][j][r] + bv_;
                    }
                }
            }
        }
        // epilogue touches no LDS; next mt's first barrier orders restaging
    }
}

// ============ GEMM variant 2 (fallback, proven R2): fp32 W convert =========
__global__ __launch_bounds__(256) void moe_gemm_kernel(
    const __hip_bfloat16* __restrict__ Ap,
    const float* __restrict__ W,
    const float* __restrict__ bias,
    const int* __restrict__ gstart,
    const int* __restrict__ perm,
    float* __restrict__ out)
{
    const int nt = blockIdx.x;
    const int e  = blockIdx.y;
    const int g0 = gstart[e];
    const int ne = gstart[e + 1] - g0;
    if (ne <= 0) return;
    const int nmt = (ne + TM - 1) / TM;
    const int n0  = nt * TNB;

    __shared__ __hip_bfloat16 Asm[TM * BK];
    __shared__ __hip_bfloat16 Bsm[TNB * BK];

    const int tid  = threadIdx.x;
    const int lane = tid & 63;
    const int wave = tid >> 6;
    const int wm   = (wave & 1) * 64;
    const int wn   = (wave >> 1) * 64;
    const int l16  = lane & 15;
    const int quad = lane >> 4;

    const int arow = wave * 16 + (lane >> 2);
    const int acol = (lane & 3) * 8;

    const float* Wb = W + ((size_t)e * VOCAB + n0) * DM;

    float bj[4];
    #pragma unroll
    for (int j = 0; j < 4; ++j)
        bj[j] = bias[(size_t)e * VOCAB + n0 + wn + j * 16 + l16];

    for (int mt = 0; mt < nmt; ++mt) {
        const int m0 = mt * TM;
        const __hip_bfloat16* Ab = Ap + (size_t)(g0 + m0) * DM;
        f32x4 acc[4][4] = {};

        for (int k0 = 0; k0 < DM; k0 += BK) {
            __syncthreads();
            #pragma unroll
            for (int t = 0; t < 2; ++t) {
                const __hip_bfloat16* src = Ab + (size_t)(t * 64 + arow) * DM + k0 + acol;
                __builtin_amdgcn_global_load_lds(
                    (const __attribute__((address_space(1))) void*)src,
                    (__attribute__((address_space(3))) void*)(Asm + (t * 64 + wave * 16) * BK),
                    16, 0, 0);
            }
            #pragma unroll
            for (int t = 0; t < 4; ++t) {
                int u   = t * 256 + tid;
                int row = u >> 3;
                int c4  = (u & 7) * 4;
                const float4 v = *(const float4*)(Wb + (size_t)row * DM + k0 + c4);
                union { __hip_bfloat162 h[2]; unsigned long long q; } cv;
                cv.h[0] = __float22bfloat162_rn(make_float2(v.x, v.y));
                cv.h[1] = __float22bfloat162_rn(make_float2(v.z, v.w));
                *(unsigned long long*)(Bsm + row * BK + c4) = cv.q;
            }
            __syncthreads();
            bf16x8 av[4], bv[4];
            #pragma unroll
            for (int i = 0; i < 4; ++i)
                av[i] = *(const bf16x8*)(Asm + (wm + i * 16 + l16) * BK + quad * 8);
            #pragma unroll
            for (int j = 0; j < 4; ++j)
                bv[j] = *(const bf16x8*)(Bsm + (wn + j * 16 + l16) * BK + quad * 8);
            #pragma unroll
            for (int i = 0; i < 4; ++i)
                #pragma unroll
                for (int j = 0; j < 4; ++j)
                    acc[i][j] = __builtin_amdgcn_mfma_f32_16x16x32_bf16(
                        av[i], bv[j], acc[i][j], 0, 0, 0);
        }

        #pragma unroll
        for (int j = 0; j < 4; ++j) {
            const int col = n0 + wn + j * 16 + l16;
            const float bv_ = bj[j];
            #pragma unroll
            for (int i = 0; i < 4; ++i) {
                #pragma unroll
                for (int r = 0; r < 4; ++r) {
                    int pr = m0 + wm + i * 16 + quad * 4 + r;
                    if (pr < ne) {
                        int orow = perm[g0 + pr];
                        out[(size_t)orow * VOCAB + col] = acc[i][j][r] + bv_;
                    }
                }
            }
        }
    }
}

extern "C" void kernel_launch(void* const* d_in, const int* in_sizes, int n_in,
                              void* d_out, int out_size, void* d_ws, size_t ws_size,
                              hipStream_t stream)
{
    const float* x   = (const float*)d_in[0];
    const int*   ptr = (const int*)d_in[1];
    const float* W   = (const float*)d_in[2];
    const float* b   = (const float*)d_in[3];
    float* out = (float*)d_out;

    char* ws = (char*)d_ws;
    int* gstart = (int*)ws;
    int* perm   = (int*)(ws + WS_PERM_OFF);
    __hip_bfloat16* Ap = (__hip_bfloat16*)(ws + WS_AP_OFF);

    route_kernel<<<1, 256, 0, stream>>>(ptr, gstart, perm);
    pack_kernel<<<BATCH + TMB, 256, 0, stream>>>(x, perm, Ap);

    if (ws_size >= WS_NEED) {
        __hip_bfloat16* Wb16 = (__hip_bfloat16*)(ws + WS_WB_OFF);
        wconv_kernel<<<2048, 256, 0, stream>>>(W, Wb16);
        dim3 grid(VOCAB / TNB, NEXP);
        moe_gemm_bf16<<<grid, 512, 0, stream>>>(Ap, Wb16, b, gstart, perm, out);
    } else {
        dim3 grid(VOCAB / TNB, NEXP);
        moe_gemm_kernel<<<grid, 256, 0, stream>>>(Ap, W, b, gstart, perm, out);
    }
}